// Round 1
// 782.630 us; speedup vs baseline: 1.0679x; 1.0679x over previous
//
#include <hip/hip_runtime.h>

typedef short s16x8 __attribute__((ext_vector_type(8)));
typedef float f32x4 __attribute__((ext_vector_type(4)));

constexpr int BATCH = 32, NODES = 512, DIM = 768, LAYERS = 4;
constexpr float QK_SCALE = 0.03608439182435161f;  // 1/sqrt(768)

constexpr size_t OUT_OFF  = 0;
constexpr size_t RET_OFF  = (size_t)BATCH * NODES * DIM;                       // 12582912
constexpr size_t ADJS_OFF = RET_OFF + (size_t)BATCH * NODES * (LAYERS + 1);    // 12664832
constexpr size_t L0_OFF   = ADJS_OFF + (size_t)BATCH * NODES * NODES * LAYERS; // 46219264
constexpr size_t C_OFF    = L0_OFF + 1;
constexpr size_t G_OFF    = C_OFF + BATCH * LAYERS;

#define DEVI static __device__ __forceinline__

DEVI float bf2f(unsigned short u) {
    union { unsigned int i; float f; } v; v.i = ((unsigned int)u) << 16; return v.f;
}
DEVI unsigned short f2bf(float f) {
    union { float f; unsigned int i; } v; v.f = f;
    return (unsigned short)((v.i + 0x7FFFu + ((v.i >> 16) & 1u)) >> 16);
}
DEVI ushort4 pk4(float4 v) {
    ushort4 o; o.x = f2bf(v.x); o.y = f2bf(v.y); o.z = f2bf(v.z); o.w = f2bf(v.w); return o;
}
DEVI float sigm(float x) { return 1.0f / (1.0f + __expf(-x)); }
DEVI float deg2dis(float d) { return d > 0.f ? rsqrtf(fmaxf(d, 1e-12f)) : 0.f; }

// async global->LDS, 16B per lane; lds base must be wave-uniform (deposit = base + lane*16)
DEVI void gload16(const unsigned short* g, unsigned short* l) {
    __builtin_amdgcn_global_load_lds(
        (const __attribute__((address_space(1))) unsigned int*)g,
        (__attribute__((address_space(3))) unsigned int*)l, 16, 0, 0);
}

// ---------------------------------------------------------------------------
// Old 128x128 NT GEMM (m97-structure). Retained for the tiny MT-prep GEMM only.
// ---------------------------------------------------------------------------
template <int MODE>
__global__ __launch_bounds__(256) void gemm_nt(
    const unsigned short* __restrict__ A0, const unsigned short* __restrict__ B0,
    unsigned short* __restrict__ C0,
    int K, int lda, int ldb, int ldc,
    long sA, long sB, long sC,
    const float* __restrict__ pmask, float* __restrict__ deg,
    unsigned short* __restrict__ adjT,
    float* __restrict__ l0_acc, float* __restrict__ c_acc, float* __restrict__ g_acc,
    int layer)
{
    __shared__ __align__(16) unsigned short As[128 * 32];
    __shared__ __align__(16) unsigned short Bs[128 * 32];

    const int tid  = threadIdx.x;
    const int lane = tid & 63;
    const int wave = tid >> 6;
    const int wr = (wave >> 1) << 6;
    const int wc = (wave & 1) << 6;
    const int z = blockIdx.z;
    const int rows0 = blockIdx.x << 7;
    const int cols0 = blockIdx.y << 7;

    const unsigned short* A = A0 + (size_t)z * sA + (size_t)rows0 * lda;
    const unsigned short* Bsrc = B0 + (size_t)z * sB + (size_t)cols0 * ldb;

    f32x4 acc[4][4] = {};

    const int srow = wave * 16 + (lane >> 2);
    const int scb  = (lane & 3) << 3;
    const unsigned short* Ag = A + (size_t)srow * lda + scb;
    const unsigned short* Bg = Bsrc + (size_t)srow * ldb + scb;
    unsigned short* lA0 = &As[wave * 512];
    unsigned short* lA1 = &As[2048 + wave * 512];
    unsigned short* lB0 = &Bs[wave * 512];
    unsigned short* lB1 = &Bs[2048 + wave * 512];
    const size_t a64 = (size_t)64 * lda, b64 = (size_t)64 * ldb;

    const int mrow = lane & 15;
    const int kq   = (lane >> 4) << 3;

    for (int kt = 0; kt < K; kt += 32) {
        __syncthreads();
        gload16(Ag + kt, lA0);
        gload16(Ag + a64 + kt, lA1);
        gload16(Bg + kt, lB0);
        gload16(Bg + b64 + kt, lB1);
        __syncthreads();

        s16x8 af[4], bfr[4];
        #pragma unroll
        for (int i = 0; i < 4; ++i) {
            af[i]  = *(const s16x8*)(&As[(wr + i * 16 + mrow) * 32 + kq]);
            bfr[i] = *(const s16x8*)(&Bs[(wc + i * 16 + mrow) * 32 + kq]);
        }
        #pragma unroll
        for (int i = 0; i < 4; ++i)
            #pragma unroll
            for (int j = 0; j < 4; ++j)
                acc[i][j] = __builtin_amdgcn_mfma_f32_16x16x32_bf16(af[i], bfr[j], acc[i][j], 0, 0, 0);
    }

    const int colb = lane & 15, quad = lane >> 4;
    unsigned short* C = C0 + (size_t)z * sC;
    #pragma unroll
    for (int i = 0; i < 4; ++i) {
        const int rbase = rows0 + wr + i * 16 + (quad << 2);
        #pragma unroll
        for (int j = 0; j < 4; ++j) {
            const int cc = cols0 + wc + j * 16 + colb;
            #pragma unroll
            for (int r = 0; r < 4; ++r)
                C[(size_t)(rbase + r) * ldc + cc] = f2bf(acc[i][j][r]);
        }
    }
}

// ---------------------------------------------------------------------------
// 256x256 8-phase NT GEMM (T2 swizzle + T3/T4 counted vmcnt + T5 setprio).
// BK=64, 512 threads = 8 waves (2M x 4N), per-wave output 128x64.
// LDS: [buf][op][half][128x64 bf16] = 128 KiB, double-buffered.
// Swizzle: LDS[row][chunk8] holds global chunk (chunk8 ^ (row&7)); gload_lds
// deposits linearly (inverse-swizzled global source), ds_read XORs the addr.
// MODE 0: plain bf16 store. MODE 1: scores epilogue (sigmoid*mask, deg/l0/c/g,
// adjT bf16 [m][n]). MODE 2: rows scaled by deg2dis(deg[row]).
// ---------------------------------------------------------------------------
template <int MODE>
__global__ __launch_bounds__(512) void gemm256_nt(
    const unsigned short* __restrict__ A0, const unsigned short* __restrict__ B0,
    unsigned short* __restrict__ C0,
    int K, int lda, int ldb, int ldc,
    long sA, long sB, long sC,
    const float* __restrict__ pmask, float* __restrict__ deg,
    unsigned short* __restrict__ adjT,
    float* __restrict__ l0_acc, float* __restrict__ c_acc, float* __restrict__ g_acc,
    int layer)
{
    __shared__ __align__(16) unsigned short lds[2][2][2][8192];
    __shared__ float pmr[256];
    __shared__ float pmc[256];

    const int tid  = threadIdx.x;
    const int lane = tid & 63;
    const int wave = tid >> 6;   // 0..7
    const int wm   = wave >> 2;  // 0..1  (M-half of the block tile)
    const int wn   = wave & 3;   // 0..3  (64-col slice)
    const int z = blockIdx.z;
    const int rows0 = blockIdx.x << 8;
    const int cols0 = blockIdx.y << 8;

    const unsigned short* A = A0 + (size_t)z * sA;
    const unsigned short* B = B0 + (size_t)z * sB;

    if constexpr (MODE == 1) {
        if (tid < 256) pmr[tid] = pmask[(size_t)z * NODES + rows0 + tid];
        else pmc[tid - 256] = pmask[(size_t)z * NODES + cols0 + (tid - 256)];
    }

    // staging: thread -> (row = 64*g + 8*wave + (lane>>3), chunk8 = lane&7),
    // global source chunk pre-swizzled: chunk ^ (ldsrow & 7) = chunk ^ (lane>>3)
    const int srow  = lane >> 3;
    const int scol8 = (lane & 7) ^ srow;

    auto stage_half = [&](int T, int op, int h) {
        const int base = (op == 0) ? rows0 : cols0;
        const int ld   = (op == 0) ? lda : ldb;
        const unsigned short* src = ((op == 0) ? A : B)
            + (size_t)(base + h * 128 + wave * 8 + srow) * ld + (size_t)T * 64 + scol8 * 8;
        unsigned short* dst = &lds[T & 1][op][h][wave * 512];
        gload16(src, dst);
        gload16(src + (size_t)64 * ld, dst + 4096);
    };

    const int nkt = K >> 6;

    // prologue: tile0 fully, tile1 first half in flight
    stage_half(0, 0, 0); stage_half(0, 0, 1);
    stage_half(0, 1, 0); stage_half(0, 1, 1);
    if (nkt > 1) {
        stage_half(1, 0, 0);
        asm volatile("s_waitcnt vmcnt(2)" ::: "memory");
    } else {
        asm volatile("s_waitcnt vmcnt(0)" ::: "memory");
    }
    __builtin_amdgcn_s_barrier();
    asm volatile("" ::: "memory");

    f32x4 acc[8][4] = {};

    const int fr = lane & 15;            // fragment row (C col within 16)
    const int fq = lane >> 4;            // quad -> 16B k sub-chunk
    const int xk = (fr & 7) << 4;        // read-side swizzle XOR (bytes)
    const int frow64 = fr * 64;          // row stride in ushorts
    const int ka0 = ((fq * 16) ^ xk) >> 1;        // kstep 0, ushort offset
    const int ka1 = ((64 + fq * 16) ^ xk) >> 1;   // kstep 1
    const int brow = (wn & 1) * 4096;    // ushort offset of wave's 64-row slice in B-half

    for (int T = 0; T < nkt; ++T) {
        const unsigned short* Ah = &lds[T & 1][0][wm][0];
        const unsigned short* Bh = &lds[T & 1][1][wn >> 1][0];
        s16x8 af[4][2], bq[4][2];

        // ---------------- phase 1: quadrant (Mfrags 0-3, Nfrags 0-1)
        #pragma unroll
        for (int i = 0; i < 4; ++i) {
            af[i][0] = *(const s16x8*)(Ah + i * 1024 + frow64 + ka0);
            af[i][1] = *(const s16x8*)(Ah + i * 1024 + frow64 + ka1);
        }
        #pragma unroll
        for (int j = 0; j < 2; ++j) {
            bq[j][0] = *(const s16x8*)(Bh + brow + j * 1024 + frow64 + ka0);
            bq[j][1] = *(const s16x8*)(Bh + brow + j * 1024 + frow64 + ka1);
        }
        if (T + 1 < nkt) stage_half(T + 1, 0, 1);
        asm volatile("" ::: "memory");
        __builtin_amdgcn_s_barrier();
        asm volatile("s_waitcnt lgkmcnt(0)" ::: "memory");
        __builtin_amdgcn_sched_barrier(0);
        __builtin_amdgcn_s_setprio(1);
        #pragma unroll
        for (int i = 0; i < 4; ++i)
            #pragma unroll
            for (int j = 0; j < 2; ++j)
                #pragma unroll
                for (int s = 0; s < 2; ++s)
                    acc[i][j] = __builtin_amdgcn_mfma_f32_16x16x32_bf16(af[i][s], bq[j][s], acc[i][j], 0, 0, 0);
        __builtin_amdgcn_s_setprio(0);
        asm volatile("" ::: "memory");
        __builtin_amdgcn_s_barrier();
        asm volatile("" ::: "memory");

        // ---------------- phase 2: quadrant (Mfrags 0-3, Nfrags 2-3)
        #pragma unroll
        for (int j = 0; j < 2; ++j) {
            bq[2 + j][0] = *(const s16x8*)(Bh + brow + (2 + j) * 1024 + frow64 + ka0);
            bq[2 + j][1] = *(const s16x8*)(Bh + brow + (2 + j) * 1024 + frow64 + ka1);
        }
        if (T + 1 < nkt) stage_half(T + 1, 1, 0);
        asm volatile("" ::: "memory");
        __builtin_amdgcn_s_barrier();
        asm volatile("s_waitcnt lgkmcnt(0)" ::: "memory");
        __builtin_amdgcn_sched_barrier(0);
        __builtin_amdgcn_s_setprio(1);
        #pragma unroll
        for (int i = 0; i < 4; ++i)
            #pragma unroll
            for (int j = 2; j < 4; ++j)
                #pragma unroll
                for (int s = 0; s < 2; ++s)
                    acc[i][j] = __builtin_amdgcn_mfma_f32_16x16x32_bf16(af[i][s], bq[j][s], acc[i][j], 0, 0, 0);
        __builtin_amdgcn_s_setprio(0);
        asm volatile("" ::: "memory");
        __builtin_amdgcn_s_barrier();
        asm volatile("" ::: "memory");

        // ---------------- phase 3: quadrant (Mfrags 4-7, Nfrags 2-3)
        #pragma unroll
        for (int i = 0; i < 4; ++i) {
            af[i][0] = *(const s16x8*)(Ah + (4 + i) * 1024 + frow64 + ka0);
            af[i][1] = *(const s16x8*)(Ah + (4 + i) * 1024 + frow64 + ka1);
        }
        if (T + 1 < nkt) stage_half(T + 1, 1, 1);
        asm volatile("" ::: "memory");
        __builtin_amdgcn_s_barrier();
        asm volatile("s_waitcnt lgkmcnt(0)" ::: "memory");
        __builtin_amdgcn_sched_barrier(0);
        __builtin_amdgcn_s_setprio(1);
        #pragma unroll
        for (int i = 0; i < 4; ++i)
            #pragma unroll
            for (int j = 2; j < 4; ++j)
                #pragma unroll
                for (int s = 0; s < 2; ++s)
                    acc[4 + i][j] = __builtin_amdgcn_mfma_f32_16x16x32_bf16(af[i][s], bq[j][s], acc[4 + i][j], 0, 0, 0);
        __builtin_amdgcn_s_setprio(0);
        asm volatile("" ::: "memory");
        __builtin_amdgcn_s_barrier();
        asm volatile("" ::: "memory");

        // ---------------- phase 4: quadrant (Mfrags 4-7, Nfrags 0-1), no ds_reads
        if (T + 2 < nkt) stage_half(T + 2, 0, 0);
        asm volatile("" ::: "memory");
        __builtin_amdgcn_s_barrier();
        asm volatile("" ::: "memory");
        __builtin_amdgcn_s_setprio(1);
        #pragma unroll
        for (int i = 0; i < 4; ++i)
            #pragma unroll
            for (int j = 0; j < 2; ++j)
                #pragma unroll
                for (int s = 0; s < 2; ++s)
                    acc[4 + i][j] = __builtin_amdgcn_mfma_f32_16x16x32_bf16(af[i][s], bq[j][s], acc[4 + i][j], 0, 0, 0);
        __builtin_amdgcn_s_setprio(0);
        // K-tile boundary: counted wait. In steady state 2 loads (next tile's A0
        // prefetch) stay in flight; at the tail nothing new was issued, so the 2
        // newest outstanding would be needed data -> full drain there.
        if (T + 2 < nkt) asm volatile("s_waitcnt vmcnt(2)" ::: "memory");
        else             asm volatile("s_waitcnt vmcnt(0)" ::: "memory");
        __builtin_amdgcn_s_barrier();
        asm volatile("" ::: "memory");
    }

    const int quad4 = fq << 2;

    if constexpr (MODE != 1) {
        unsigned short* C = C0 + (size_t)z * sC;
        #pragma unroll
        for (int i = 0; i < 8; ++i) {
            const int rbase = rows0 + wm * 128 + i * 16 + quad4;
            float dv[4];
            if constexpr (MODE == 2) {
                #pragma unroll
                for (int r = 0; r < 4; ++r) dv[r] = deg2dis(deg[(size_t)z * NODES + rbase + r]);
            }
            #pragma unroll
            for (int j = 0; j < 4; ++j) {
                const int cc = cols0 + wn * 64 + j * 16 + fr;
                #pragma unroll
                for (int r = 0; r < 4; ++r) {
                    float v = acc[i][j][r];
                    if constexpr (MODE == 2) v *= dv[r];
                    C[(size_t)(rbase + r) * ldc + cc] = f2bf(v);
                }
            }
        }
    } else {
        float tot = 0.f, gs = 0.f, cs = 0.f;
        #pragma unroll
        for (int i = 0; i < 8; ++i) {
            const int nloc = wm * 128 + i * 16 + quad4;
            #pragma unroll
            for (int r = 0; r < 4; ++r) {
                const int n = rows0 + nloc + r;
                const float pmn = pmr[nloc + r];
                float dp = 0.f;
                #pragma unroll
                for (int j = 0; j < 4; ++j) {
                    const int mloc = wn * 64 + j * 16 + fr;
                    const int m = cols0 + mloc;
                    float a = pmn * pmc[mloc] * sigm(acc[i][j][r] * QK_SCALE);
                    acc[i][j][r] = a;
                    dp += a;
                    tot += a;
                    if (m < NODES - 1) {
                        if (n < NODES - 1) gs += a;
                        else cs += a;
                    }
                }
                dp += __shfl_xor(dp, 1, 16);
                dp += __shfl_xor(dp, 2, 16);
                dp += __shfl_xor(dp, 4, 16);
                dp += __shfl_xor(dp, 8, 16);
                if (fr == 0) atomicAdd(&deg[(size_t)z * NODES + n], dp);
            }
        }
        // adj^T (bf16, [b][m][n]) into this layer's slice (also feeds agg GEMM)
        #pragma unroll
        for (int i = 0; i < 8; ++i) {
            const int nb = rows0 + wm * 128 + i * 16 + quad4;
            #pragma unroll
            for (int j = 0; j < 4; ++j) {
                const int m = cols0 + wn * 64 + j * 16 + fr;
                ushort4 pk;
                pk.x = f2bf(acc[i][j][0]); pk.y = f2bf(acc[i][j][1]);
                pk.z = f2bf(acc[i][j][2]); pk.w = f2bf(acc[i][j][3]);
                *(ushort4*)(adjT + ((size_t)z * NODES + m) * NODES + nb) = pk;
            }
        }
        #pragma unroll
        for (int o = 1; o < 64; o <<= 1) {
            tot += __shfl_xor(tot, o, 64);
            gs  += __shfl_xor(gs, o, 64);
            cs  += __shfl_xor(cs, o, 64);
        }
        if (lane == 0) {
            atomicAdd(l0_acc, tot);
            atomicAdd(&g_acc[z * LAYERS + layer], gs);
            atomicAdd(&c_acc[z * LAYERS + layer], cs);
        }
    }
}

// ---------------------------------------------------------------------------
// adjs[b][n][m][l] = f32(adjT[l][b][m][n])  — LDS-transposed, coalesced stores
// ---------------------------------------------------------------------------
__global__ __launch_bounds__(256) void interleave_adjs(
    const unsigned short* __restrict__ adjT, float* __restrict__ adjs)
{
    __shared__ unsigned short t[4][32][36];
    const int b = blockIdx.z, m0 = blockIdx.x << 5, n0 = blockIdx.y << 5;
    const int tr = threadIdx.x >> 3, tc = (threadIdx.x & 7) << 2;
    #pragma unroll
    for (int l = 0; l < LAYERS; ++l) {
        ushort4 v = *(const ushort4*)(adjT + (((size_t)l * BATCH + b) * NODES + m0 + tr) * NODES + n0 + tc);
        t[l][tr][tc] = v.x; t[l][tr][tc + 1] = v.y; t[l][tr][tc + 2] = v.z; t[l][tr][tc + 3] = v.w;
    }
    __syncthreads();
    float* dst = adjs + (((size_t)b * NODES + n0 + tr) * NODES + m0 + tc) * LAYERS;
    #pragma unroll
    for (int mm = 0; mm < 4; ++mm) {
        float4 f;
        f.x = bf2f(t[0][tc + mm][tr]); f.y = bf2f(t[1][tc + mm][tr]);
        f.z = bf2f(t[2][tc + mm][tr]); f.w = bf2f(t[3][tc + mm][tr]);
        *(float4*)(dst + mm * 4) = f;
    }
}

// ---------------------------------------------------------------------------
// fp_t[b][d][n] = bf16(deg2dis(deg[b][n]) * X[b][n][d])   (X bf16)
// ---------------------------------------------------------------------------
__global__ void fp_transpose(const unsigned short* __restrict__ X, const float* __restrict__ deg,
                             unsigned short* __restrict__ fpt)
{
    __shared__ unsigned short t[32][36];
    const int b = blockIdx.z;
    const int n0 = blockIdx.x << 5, d0 = blockIdx.y << 5;
    const int tr = threadIdx.x >> 3, tc = (threadIdx.x & 7) << 2;
    const float dv = deg2dis(deg[(size_t)b * NODES + n0 + tr]);
    ushort4 v = *(const ushort4*)(X + ((size_t)b * NODES + n0 + tr) * DIM + d0 + tc);
    t[tr][tc]     = f2bf(bf2f(v.x) * dv);
    t[tr][tc + 1] = f2bf(bf2f(v.y) * dv);
    t[tr][tc + 2] = f2bf(bf2f(v.z) * dv);
    t[tr][tc + 3] = f2bf(bf2f(v.w) * dv);
    __syncthreads();
    ushort4 o;
    o.x = t[tc + 0][tr]; o.y = t[tc + 1][tr]; o.z = t[tc + 2][tr]; o.w = t[tc + 3][tr];
    *(ushort4*)(fpt + ((size_t)b * DIM + d0 + tr) * NODES + n0 + tc) = o;
}

// ---------------------------------------------------------------------------
// Combined f32->bf16 cast: feat (12288 blk), Wq (2304 blk), Wk (2304 blk)
// ---------------------------------------------------------------------------
__global__ void cast_all(const float* __restrict__ feat, const float* __restrict__ Wq,
                         const float* __restrict__ Wk, unsigned short* __restrict__ featb,
                         unsigned short* __restrict__ Wqb, unsigned short* __restrict__ Wkb)
{
    const int bx = blockIdx.x;
    const float* src; unsigned short* dst; size_t base;
    if (bx < 12288)      { src = feat; dst = featb; base = (size_t)bx * 1024; }
    else if (bx < 14592) { src = Wq;   dst = Wqb;   base = (size_t)(bx - 12288) * 1024; }
    else                 { src = Wk;   dst = Wkb;   base = (size_t)(bx - 14592) * 1024; }
    const size_t i = base + ((size_t)threadIdx.x << 2);
    float4 v = *(const float4*)(src + i);
    *(ushort4*)(dst + i) = pk4(v);
}

__global__ void psum_kernel(const float* __restrict__ pm, float* __restrict__ ps)
{
    const int b = blockIdx.x, t = threadIdx.x;
    float s = pm[(size_t)b * NODES + t] + pm[(size_t)b * NODES + 256 + t];
    #pragma unroll
    for (int o = 1; o < 64; o <<= 1) s += __shfl_xor(s, o, 64);
    __shared__ float sh[4];
    if ((t & 63) == 0) sh[t >> 6] = s;
    __syncthreads();
    if (t == 0) ps[b] = sh[0] + sh[1] + sh[2] + sh[3];
}

// ---------------------------------------------------------------------------
// Final fused output: all 5 preds in one pass. One wave per (b,n) row.
// Also (block 0) finalizes c/g sparsity and l0 scalar.
// ---------------------------------------------------------------------------
__global__ __launch_bounds__(256) void final_out(
    const float* __restrict__ X0f, const unsigned short* __restrict__ X1,
    const unsigned short* __restrict__ X2, const unsigned short* __restrict__ X3,
    const unsigned short* __restrict__ X4,
    const float* __restrict__ pw, const float* __restrict__ pb,
    const float* __restrict__ ps, const float* __restrict__ c_acc,
    const float* __restrict__ g_acc, const float* __restrict__ l0,
    float* __restrict__ ob)
{
    if (blockIdx.x == 0) {
        const int t = threadIdx.x;
        if (t < BATCH * LAYERS) {
            const int b = t >> 2;
            const float p = ps[b];
            ob[C_OFF + t] = c_acc[t] / p;
            ob[G_OFF + t] = g_acc[t] / (p * p);
        }
        if (t == 0) {
            float fs = 1e-8f;
            for (int b = 0; b < BATCH; ++b) fs += ps[b] * ps[b];
            ob[L0_OFF] = l0[0] / (fs * (float)LAYERS);
        }
    }

    const int row = (blockIdx.x << 2) + (threadIdx.x >> 6);
    const int lane = threadIdx.x & 63;
    const unsigned short* Xb[4] = { X1 + (size_t)row * DIM, X2 + (size_t)row * DIM,
                                    X3 + (size_t)row * DIM, X4 + (size_t)row * DIM };
    float xs[5][12];
    float dot[5] = {};
    #pragma unroll
    for (int c = 0; c < 3; ++c) {
        const int idx = c * 256 + (lane << 2);
        float4 wv = *(const float4*)(pw + idx);
        float4 x0 = *(const float4*)(X0f + (size_t)row * DIM + idx);
        xs[0][c * 4 + 0] = x0.x; xs[0][c * 4 + 1] = x0.y;
        xs[0][c * 4 + 2] = x0.z; xs[0][c * 4 + 3] = x0.w;
        dot[0] += x0.x * wv.x + x0.y * wv.y + x0.z * wv.z + x0.w * wv.w;
        #pragma unroll
        for (int l = 0; l < 4; ++l) {
            ushort4 xv = *(const ushort4*)(Xb[l] + idx);
            float a0 = bf2f(xv.x), a1 = bf2f(xv.y), a2 = bf2f(xv.z), a3 = bf2f(xv.w);
            xs[l + 1][c * 4 + 0] = a0; xs[l + 1][c * 4 + 1] = a1;
            xs[l + 1][c * 4 + 2] = a2; xs[l + 1][c * 4 + 3] = a3;
            dot[l + 1] += a0 * wv.x + a1 * wv.y + a2 * wv.z + a3 * wv.w;
        }
    }
    #pragma unroll
    for (int l = 0; l < 5; ++l)
        #pragma unroll
        for (int o = 1; o < 64; o <<= 1) dot[l] += __shfl_xor(dot[l], o, 64);
    const float pbv = pb[0];
    float r[5];
    #pragma unroll
    for (int l = 0; l < 5; ++l) r[l] = sigm(dot[l] + pbv);
    if (lane == 0) {
        float* rr = ob + RET_OFF + (size_t)row * (LAYERS + 1);
        rr[0] = r[0]; rr[1] = r[1]; rr[2] = r[2]; rr[3] = r[3]; rr[4] = r[4];
    }
    float* orow = ob + OUT_OFF + (size_t)row * DIM;
    #pragma unroll
    for (int c = 0; c < 3; ++c) {
        float4 p;
        p.x = r[0] * xs[0][c * 4 + 0]; p.y = r[0] * xs[0][c * 4 + 1];
        p.z = r[0] * xs[0][c * 4 + 2]; p.w = r[0] * xs[0][c * 4 + 3];
        #pragma unroll
        for (int l = 1; l < 5; ++l) {
            p.x += r[l] * xs[l][c * 4 + 0]; p.y += r[l] * xs[l][c * 4 + 1];
            p.z += r[l] * xs[l][c * 4 + 2]; p.w += r[l] * xs[l][c * 4 + 3];
        }
        *(float4*)(orow + c * 256 + (lane << 2)) = p;
    }
}

// ---------------------------------------------------------------------------
extern "C" void kernel_launch(void* const* d_in, const int* in_sizes, int n_in,
                              void* d_out, int out_size, void* d_ws, size_t ws_size,
                              hipStream_t stream)
{
    (void)in_sizes; (void)n_in; (void)out_size; (void)ws_size;
    const float* pmask = (const float*)d_in[0];
    const float* feat  = (const float*)d_in[1];
    const float* Wq    = (const float*)d_in[2];
    const float* Wk    = (const float*)d_in[3];
    const float* projw = (const float*)d_in[4];
    const float* projb = (const float*)d_in[5];
    float* ob = (float*)d_out;

    char* w = (char*)d_ws;
    unsigned short* Xb[4];                                     // bf16 [B,N,D] per layer
    Xb[0] = (unsigned short*)(w + 0);
    Xb[1] = (unsigned short*)(w + 25165824);
    Xb[2] = (unsigned short*)(w + 50331648);
    Xb[3] = (unsigned short*)(w + 75497472);
    unsigned short* qws   = (unsigned short*)(w + 100663296);  //  25165824 B bf16 t / fp_t
    unsigned short* featb = (unsigned short*)(w + 125829120);  //  25165824 B bf16 feat
    unsigned short* adjT  = (unsigned short*)(w + 150994944);  //  67108864 B bf16 [L,B,m,n]
    unsigned short* Wqb   = (unsigned short*)(w + 218103808);  //   4718592 B bf16 [L,D,D]
    unsigned short* Wkb   = (unsigned short*)(w + 222822400);  //   4718592 B bf16 [L,D,D]
    unsigned short* MT    = (unsigned short*)(w + 227540992);  //   4718592 B bf16 [L,D,D]  MT[l][j][i]
    float* deg_all = (float*)(w + 232259584);                  //    262144 B f32 [L,B,N]
    float* c_acc   = (float*)(w + 232521728);                  //       512 B
    float* g_acc   = (float*)(w + 232522240);                  //       512 B
    float* l0_acc  = (float*)(w + 232522752);                  //       256 B
    float* p_sum   = (float*)(w + 232523008);                  //       256 B

    dim3 blk(256);
    dim3 blk5(512);
    hipMemsetAsync(w + 232259584, 0, 263680, stream);  // deg_all + c_acc + g_acc + l0_acc

    cast_all<<<dim3(16896), blk, 0, stream>>>(feat, Wq, Wk, featb, Wqb, Wkb);
    psum_kernel<<<dim3(32), blk, 0, stream>>>(pmask, p_sum);

    // MT[l] = Wk[l] @ Wq[l]^T  (NT, batched over layers): MT[j][i] = sum_e Wk[j][e]Wq[i][e]
    gemm_nt<0><<<dim3(6, 6, 4), blk, 0, stream>>>(
        Wkb, Wqb, MT, DIM, DIM, DIM, DIM,
        (long)DIM * DIM, (long)DIM * DIM, (long)DIM * DIM,
        nullptr, nullptr, nullptr, nullptr, nullptr, nullptr, 0);

    for (int l = 0; l < LAYERS; ++l) {
        float* deg_l = deg_all + (size_t)l * BATCH * NODES;
        unsigned short* adjT_l = adjT + (size_t)l * BATCH * NODES * NODES;
        const unsigned short* Xsrc = (l == 0) ? featb : Xb[l - 1];

        // t = X @ M[l]   (t[n][j] = sum_i X[n][i] MT[j][i])
        gemm256_nt<0><<<dim3(64, 3, 1), blk5, 0, stream>>>(
            Xsrc, MT + (size_t)l * DIM * DIM, qws,
            DIM, DIM, DIM, DIM, 0L, 0L, 0L,
            nullptr, nullptr, nullptr, nullptr, nullptr, nullptr, 0);

        // S = t @ X^T (batched) + sigmoid/mask/stats epilogue, writes adjT_l
        gemm256_nt<1><<<dim3(2, 2, 32), blk5, 0, stream>>>(
            qws, Xsrc, nullptr,
            DIM, DIM, DIM, 0, (long)NODES * DIM, (long)NODES * DIM, 0L,
            pmask, deg_l, adjT_l, l0_acc, c_acc, g_acc, l);

        fp_transpose<<<dim3(16, 24, 32), blk, 0, stream>>>(Xsrc, deg_l, qws);

        // X' = dis[m] * (adjT_l @ (dis[n]*X))  (batched)
        gemm256_nt<2><<<dim3(2, 3, 32), blk5, 0, stream>>>(
            adjT_l, qws, Xb[l],
            NODES, NODES, NODES, DIM, (long)NODES * NODES, (long)DIM * NODES, (long)NODES * DIM,
            nullptr, deg_l, nullptr, nullptr, nullptr, nullptr, 0);
    }

    interleave_adjs<<<dim3(16, 16, 32), blk, 0, stream>>>(adjT, ob + ADJS_OFF);
    final_out<<<dim3(4096), blk, 0, stream>>>(feat, Xb[0], Xb[1], Xb[2], Xb[3],
                                              projw, projb, p_sum, c_acc, g_acc, l0_acc, ob);
}